// Round 17
// baseline (179.886 us; speedup 1.0000x reference)
//
#include <hip/hip_runtime.h>
#include <hip/hip_bf16.h>

typedef __bf16 bf16;
typedef __bf16 bf16x4 __attribute__((ext_vector_type(4)));
typedef __bf16 bf16x8 __attribute__((ext_vector_type(8)));
typedef float f32x4 __attribute__((ext_vector_type(4)));

#define DIM 768
#define HW 1024          // 32*32
#define BATCH 16
#define M_TOTAL (BATCH * HW)   // 16384
#define NKT 12                 // K-tiles of 64

#define AS1 __attribute__((address_space(1)))
#define AS3 __attribute__((address_space(3)))

// ======================== k-permutation convention =========================
// All bf16 [.][768] activation buffers and Wb[768][768] store the k (channel)
// dimension permuted within each 32-group: physical position p = 8g+j holds
// logical k = 4g+j (j<4) or 16+4g+(j-4) (j>=4). mfma_f32_16x16x32_bf16
// fragments are then CONTIGUOUS 16B both in LDS and in GLOBAL memory ->
// single ds_read_b128 OR global_load_dwordx4 per fragment.
// k2pos(kk) = (((kk&15)>>2)<<3)+(kk&3)+((kk>>4)<<2). (validated R4-R16)

// ------------- prep: weights f32->bf16 k-permuted + x NCHW -> [n][c] bf16 -------------
__global__ void prep_kernel(const float* __restrict__ x, bf16* __restrict__ xb,
                            const float4* __restrict__ w1, const float4* __restrict__ w2,
                            const float4* __restrict__ w3,
                            bf16x8* __restrict__ o1, bf16x8* __restrict__ o2,
                            bf16x8* __restrict__ o3) {
    __shared__ float tile[32][33];
    if (blockIdx.x < 864) {
        const int b = blockIdx.x;
        const int which = b / 288;
        const int i = (b % 288) * 256 + threadIdx.x;
        const float4* w = which == 0 ? w1 : which == 1 ? w2 : w3;
        bf16x8* o = which == 0 ? o1 : which == 1 ? o2 : o3;
        const int row = i / 96, br = i % 96;
        const int q = br >> 2, g = br & 3;
        float4 lo = w[row * 192 + q * 8 + g];
        float4 hi = w[row * 192 + q * 8 + g + 4];
        bf16x8 r = { (bf16)lo.x, (bf16)lo.y, (bf16)lo.z, (bf16)lo.w,
                     (bf16)hi.x, (bf16)hi.y, (bf16)hi.z, (bf16)hi.w };
        o[row * 96 + br] = r;
    } else {
        const int e = blockIdx.x - 864;
        const int b = e / 768;
        const int rem = e % 768;
        const int c0 = (rem / 32) * 32;
        const int hw0 = (rem % 32) * 32;
        const int tx = threadIdx.x & 31, ty = threadIdx.x >> 5;  // 32 x 8

        const float* src = x + ((size_t)b * DIM + c0) * HW + hw0;
#pragma unroll
        for (int j = 0; j < 4; j++)
            tile[ty + 8 * j][tx] = src[(size_t)(ty + 8 * j) * HW + tx];
        __syncthreads();
        const int ptx = (((tx & 15) >> 2) << 3) + (tx & 3) + ((tx >> 4) << 2);  // k2pos
        bf16* dst = xb + ((size_t)b * HW + hw0) * DIM + c0;
#pragma unroll
        for (int j = 0; j < 4; j++)
            dst[(size_t)(ty + 8 * j) * DIM + ptx] = (bf16)tile[tx][ty + 8 * j];
    }
}

// -------- GEMM: 128x192 tile, BK=64, 4 waves (2x2), hybrid A-reg / B-LDS --------
// R17 lever (pipe-level): A-fragments load DIRECT global->register (contiguous
// 16B in k-perm layout; 16 rows x 64B coalesced; L1-hot, 2x shared), register
// double-buffered one K-tile ahead (compiler auto-inserts counted vmcnt for
// reg deps). Only B goes through LDS (48 KB dbuf -> 2 blocks/CU). LDS traffic
// per K-tile drops ~40%; ONE barrier per K-tile: lgkmcnt(0) [B reads drained]
// + vmcnt(8) [B(kt+1) resident; the 8 A-loads issued after it still fly].
// grid = 128 m-tiles x 4 n-tiles = 512 blocks = 2/CU (2 barrier domains).
// MODE 0: write bf16 [n][768] k-permuted (+bias). MODE 1: write f32 NCHW (+bias).
template <int MODE>
__global__ __launch_bounds__(256, 2) void gemm_kernel(
    const bf16* __restrict__ A,   // [M][768] k-permuted
    const bf16* __restrict__ Bw,  // [768][768] rows linear, cols k-permuted
    const float* __restrict__ bias,
    void* __restrict__ out)
{
    constexpr int K = DIM;
    __shared__ bf16 ldsB[2][192][64];   // 48 KiB -> 2 blocks/CU

    const int t = threadIdx.x;
    const int lane = t & 63;
    const int wave = t >> 6;
    const int wm = wave >> 1, wn = wave & 1;   // 2 x 2 -> wave tile 64 x 96

    const int bid = blockIdx.x;                 // 512 blocks, 512%8==0
    const int virt = (bid & 7) * 64 + (bid >> 3);
    const int m0 = (virt >> 2) * 128;           // 128 m-tiles
    const int n0 = (virt & 3) * 192;            // 4 n-tiles (n fastest: share A)

    const int fr = lane & 15;
    const int fq = lane >> 4;

    f32x4 acc[4][6] = {};

    const int s_r = t >> 3;     // 0..31, staging row within half-chunk
    const int s_blk = t & 7;    // staging 16B block in row

    // B chunk c: rows c*64 .. c*64+63  (2 gloads/thread)
    auto stageB = [&](int kt, int c) {
        const int d = kt & 1;
#pragma unroll
        for (int j = 0; j < 2; j++) {
            const int r = c * 64 + s_r + j * 32;
            __builtin_amdgcn_global_load_lds(
                (const AS1 void*)(Bw + (size_t)(n0 + r) * K + kt * 64 + ((s_blk ^ (r & 7)) << 3)),
                (AS3 void*)&ldsB[d][r][s_blk * 8], 16, 0, 0);
        }
    };

    // per-wave A-fragment base (element offset); frag (mi,ks) at +kt*64+ks*32+fq*8
    const int aBase = (m0 + wm * 64 + fr) * K + fq * 8;

    bf16x8 aP[8], aQ[8], b[12];

#define LDA(dst, kt) do { \
    _Pragma("unroll") for (int mi = 0; mi < 4; mi++) \
    _Pragma("unroll") for (int ks = 0; ks < 2; ks++) \
        dst[mi * 2 + ks] = *(const bf16x8*)(A + aBase + mi * 16 * K + (kt) * 64 + ks * 32); } while (0)

    auto ldB = [&](int kt) {           // 12 x ds_read_b128 (6 n-frags x 2 ks)
        const int d = kt & 1;
#pragma unroll
        for (int j = 0; j < 6; j++) {
            const int R = wn * 96 + j * 16 + fr;
            const bf16* rp = &ldsB[d][R][0];
            const int s = R & 7;
#pragma unroll
            for (int ks = 0; ks < 2; ks++)
                b[j * 2 + ks] = *(const bf16x8*)(rp + (((ks * 4 + fq) ^ s) << 3));
        }
    };
    auto MM = [&](const bf16x8* src) { // 48 MFMA, setprio-wrapped
        __builtin_amdgcn_s_setprio(1);
#pragma unroll
        for (int mi = 0; mi < 4; mi++)
#pragma unroll
            for (int j = 0; j < 6; j++)
#pragma unroll
                for (int ks = 0; ks < 2; ks++)
                    acc[mi][j] = __builtin_amdgcn_mfma_f32_16x16x32_bf16(
                        src[mi * 2 + ks], b[j * 2 + ks], acc[mi][j], 0, 0, 0);
        __builtin_amdgcn_s_setprio(0);
    };

    // K-tile body: stage B(kt+1) FIRST, then A(kt+1) regs (so vmcnt(8) at the
    // barrier = B resident, A still flying), then B ds_reads + MFMA on kt.
    auto body = [&](int kt, const bf16x8* cur, bf16x8* nxt) {
        const bool more = (kt + 1 < NKT);
        if (more) { stageB(kt + 1, 0); stageB(kt + 1, 1); stageB(kt + 1, 2); }
        if (more) { LDA(nxt, kt + 1); }
        ldB(kt);
        MM(cur);
        if (more) {
            asm volatile("s_waitcnt lgkmcnt(0)" ::: "memory");   // my B reads drained
            asm volatile("s_waitcnt vmcnt(8)" ::: "memory");     // B(kt+1) resident
            __builtin_amdgcn_s_barrier();
            __builtin_amdgcn_sched_barrier(0);
        }
    };

    // prologue: B(0) staged + A(0) in regs
    stageB(0, 0); stageB(0, 1); stageB(0, 2);
    LDA(aP, 0);
    asm volatile("s_waitcnt vmcnt(8)" ::: "memory");
    __builtin_amdgcn_s_barrier();

#pragma unroll 1
    for (int kt2 = 0; kt2 < NKT; kt2 += 2) {
        body(kt2, aP, aQ);
        body(kt2 + 1, aQ, aP);
    }
#undef LDA

    // ---------------- epilogue ----------------
    const int fq4 = fq * 4;
    if (MODE == 0) {
        bf16* o = (bf16*)out;
#pragma unroll
        for (int mi = 0; mi < 4; mi++) {
            const int row = m0 + wm * 64 + mi * 16 + fq4;
#pragma unroll
            for (int j = 0; j < 6; j++) {
                const int gcol = n0 + wn * 96 + j * 16 + fr;   // logical channel
                const int kk = gcol & 31;
                const int pcol = (gcol & ~31) + (((kk & 15) >> 2) << 3) + (kk & 3)
                               + ((kk >> 4) << 2);             // k2pos
                const float bv = bias[gcol];
#pragma unroll
                for (int r = 0; r < 4; r++)
                    o[(size_t)(row + r) * DIM + pcol] = (bf16)(acc[mi][j][r] + bv);
            }
        }
    } else {
        float* o = (float*)out;
#pragma unroll
        for (int mi = 0; mi < 4; mi++) {
            const int nb = m0 + wm * 64 + mi * 16 + fq4;
            const int bI = nb >> 10, hw = nb & 1023;
#pragma unroll
            for (int j = 0; j < 6; j++) {
                const int col = n0 + wn * 96 + j * 16 + fr;
                f32x4 v = acc[mi][j] + bias[col];
                *(f32x4*)(o + ((size_t)bI * DIM + col) * HW + hw) = v;
            }
        }
    }
}

// ---------------- LayerNorm + exact GELU, in-place on k-permuted bf16 rows ----------------
__global__ __launch_bounds__(256) void ln_gelu_kernel(
    bf16* __restrict__ h, const float* __restrict__ g, const float* __restrict__ beta)
{
    const int wave = threadIdx.x >> 6;
    const int lane = threadIdx.x & 63;
    const int n = blockIdx.x * 4 + wave;
    bf16* row = h + (size_t)n * DIM;

    float v[12];
    float s = 0.f, ss = 0.f;
#pragma unroll
    for (int j = 0; j < 3; j++) {
        bf16x4 x = *(const bf16x4*)(row + j * 256 + lane * 4);
#pragma unroll
        for (int i = 0; i < 4; i++) {
            float f = (float)x[i];
            v[j * 4 + i] = f;
            s += f;
            ss += f * f;
        }
    }
#pragma unroll
    for (int off = 32; off > 0; off >>= 1) {
        s += __shfl_xor(s, off);
        ss += __shfl_xor(ss, off);
    }
    const float mu = s * (1.f / DIM);
    const float var = ss * (1.f / DIM) - mu * mu;
    const float rstd = rsqrtf(var + 1e-6f);

#pragma unroll
    for (int j = 0; j < 3; j++) {
        bf16x4 r;
#pragma unroll
        for (int i = 0; i < 4; i++) {
            const int c = j * 256 + lane * 4 + i;   // physical position
            const int p = (lane * 4 + i) & 31;
            const int kk = ((p >> 3) << 2) + (p & 7) + ((p & 4) ? 12 : 0);  // pos2k
            const int gi = (c & ~31) + kk;          // logical channel for gamma/beta
            float y = (v[j * 4 + i] - mu) * rstd * g[gi] + beta[gi];
            y = 0.5f * y * (1.f + erff(y * 0.70710678118f));
            r[i] = (bf16)y;
        }
        *(bf16x4*)(row + j * 256 + lane * 4) = r;
    }
}

extern "C" void kernel_launch(void* const* d_in, const int* in_sizes, int n_in,
                              void* d_out, int out_size, void* d_ws, size_t ws_size,
                              hipStream_t stream) {
    const float* x   = (const float*)d_in[0];
    const float* W1  = (const float*)d_in[1];
    const float* b1  = (const float*)d_in[2];
    const float* g1  = (const float*)d_in[3];
    const float* be1 = (const float*)d_in[4];
    const float* W2  = (const float*)d_in[5];
    const float* b2  = (const float*)d_in[6];
    const float* g2  = (const float*)d_in[7];
    const float* be2 = (const float*)d_in[8];
    const float* W3  = (const float*)d_in[9];
    const float* b3  = (const float*)d_in[10];
    float* out = (float*)d_out;

    bf16* Wb1  = (bf16*)d_ws;
    bf16* Wb2  = Wb1 + (size_t)DIM * DIM;
    bf16* Wb3  = Wb2 + (size_t)DIM * DIM;
    bf16* buf0 = Wb3 + (size_t)DIM * DIM;          // 16384*768 bf16
    bf16* buf1 = buf0 + (size_t)M_TOTAL * DIM;

    // weights -> bf16 k-permuted + x NCHW -> [n][c] bf16 k-permuted (one launch)
    prep_kernel<<<864 + 12288, 256, 0, stream>>>(
        x, buf0, (const float4*)W1, (const float4*)W2, (const float4*)W3,
        (bf16x8*)Wb1, (bf16x8*)Wb2, (bf16x8*)Wb3);

    const int ggrid = (M_TOTAL / 128) * (DIM / 192);   // 128*4 = 512 = 2/CU
    // layer 1
    gemm_kernel<0><<<ggrid, 256, 0, stream>>>(buf0, Wb1, b1, buf1);
    ln_gelu_kernel<<<M_TOTAL / 4, 256, 0, stream>>>(buf1, g1, be1);
    // layer 2
    gemm_kernel<0><<<ggrid, 256, 0, stream>>>(buf1, Wb2, b2, buf0);
    ln_gelu_kernel<<<M_TOTAL / 4, 256, 0, stream>>>(buf0, g2, be2);
    // layer 3 -> NCHW f32 output
    gemm_kernel<1><<<ggrid, 256, 0, stream>>>(buf0, Wb3, b3, out);
}